// Round 1
// baseline (864.138 us; speedup 1.0000x reference)
//
#include <hip/hip_runtime.h>

// SparseEncoder4D: gather-GEMM-scatter sparse conv (1->8->8->1) + dense scatter.
// N=150000 voxels, K=81 offsets, C_HID=8, dense grid [2,4,32,256,256]=16.7M cells.

#define KK 81
#define CH 8
#define BB 2
#define TT 4
#define ZZ 32
#define YY 256
#define XX 256

__global__ __launch_bounds__(256) void k_zero(float4* __restrict__ out, int n4) {
    int i = blockIdx.x * blockDim.x + threadIdx.x;
    if (i < n4) out[i] = make_float4(0.f, 0.f, 0.f, 0.f);
}

// Layer 1: h1[n,c] = relu( sum_k mask[n,k]*feats[nbr_idx[n,k]] * w1[k,0,c] )
__global__ __launch_bounds__(256) void k_h1(const float* __restrict__ feats,
                                            const float* __restrict__ w1,
                                            const int* __restrict__ nbr_idx,
                                            const int* __restrict__ nbr_mask,
                                            float* __restrict__ h1, int n_total) {
    int n = blockIdx.x * blockDim.x + threadIdx.x;
    if (n >= n_total) return;
    const int* ip = nbr_idx + (long)n * KK;
    const int* mp = nbr_mask + (long)n * KK;
    float acc[CH];
#pragma unroll
    for (int c = 0; c < CH; c++) acc[c] = 0.f;
    for (int k = 0; k < KK; k++) {
        float fm = (float)mp[k];              // mask in {0,1}
        float f = feats[ip[k]] * fm;          // gather (table L2-resident)
        // w1 row is wave-uniform (same k for all lanes) -> compiler s_load
#pragma unroll
        for (int c = 0; c < CH; c++) acc[c] += f * w1[k * CH + c];
    }
    float4 r0 = make_float4(fmaxf(acc[0], 0.f), fmaxf(acc[1], 0.f),
                            fmaxf(acc[2], 0.f), fmaxf(acc[3], 0.f));
    float4 r1 = make_float4(fmaxf(acc[4], 0.f), fmaxf(acc[5], 0.f),
                            fmaxf(acc[6], 0.f), fmaxf(acc[7], 0.f));
    float4* o = (float4*)(h1 + (long)n * CH);
    o[0] = r0;
    o[1] = r1;
}

// Layer 2 + head: out[n] = sum_c relu( sum_{k,cin} m*h1[nbr,cin]*w2[k,cin,c] ) * w_out[c]
__global__ __launch_bounds__(256) void k_h2(const float* __restrict__ h1,
                                            const float* __restrict__ w2,
                                            const float* __restrict__ w_out,
                                            const int* __restrict__ nbr_idx,
                                            const int* __restrict__ nbr_mask,
                                            float* __restrict__ outf, int n_total) {
    int n = blockIdx.x * blockDim.x + threadIdx.x;
    if (n >= n_total) return;
    const int* ip = nbr_idx + (long)n * KK;
    const int* mp = nbr_mask + (long)n * KK;
    float acc[CH];
#pragma unroll
    for (int c = 0; c < CH; c++) acc[c] = 0.f;
    for (int k = 0; k < KK; k++) {
        float fm = (float)mp[k];
        const float4* g = (const float4*)(h1 + (long)ip[k] * CH);  // 32B gather, 16B-aligned
        float4 ga = g[0], gb = g[1];
        ga.x *= fm; ga.y *= fm; ga.z *= fm; ga.w *= fm;
        gb.x *= fm; gb.y *= fm; gb.z *= fm; gb.w *= fm;
        const float* wk = w2 + k * CH * CH;   // wave-uniform -> s_load, SGPR FMA operand
#pragma unroll
        for (int d = 0; d < CH; d++) {
            acc[d] += ga.x * wk[0 * CH + d] + ga.y * wk[1 * CH + d] +
                      ga.z * wk[2 * CH + d] + ga.w * wk[3 * CH + d] +
                      gb.x * wk[4 * CH + d] + gb.y * wk[5 * CH + d] +
                      gb.z * wk[6 * CH + d] + gb.w * wk[7 * CH + d];
        }
    }
    float o = 0.f;
#pragma unroll
    for (int c = 0; c < CH; c++) o += fmaxf(acc[c], 0.f) * w_out[c];
    outf[n] = o;
}

__device__ __forceinline__ int cell_of(const int* coords, const int* batch, int n) {
    // coords[n] = (x, y, z, t); dense[b, t, z, y, x]
    int4 c = *(const int4*)(coords + 4 * n);  // 16B-aligned (4 ints per row)
    int b = batch[n];
    return (((b * TT + c.w) * ZZ + c.z) * YY + c.y) * XX + c.x;
}

// Pass A: deterministic winner election — numpy fancy-assignment is last-write-wins
// in index order, i.e. largest n wins. Cells hold 0 (from k_zero); store n+1 >= 1.
__global__ __launch_bounds__(256) void k_scat_max(const int* __restrict__ coords,
                                                  const int* __restrict__ batch,
                                                  int* __restrict__ dsti, int n_total) {
    int n = blockIdx.x * blockDim.x + threadIdx.x;
    if (n >= n_total) return;
    atomicMax(dsti + cell_of(coords, batch, n), n + 1);
}

// Pass B: only the winner overwrites its cell with the float value. Losers read
// either winner's n+1 (!= theirs) or the winner's float bits (>= ~1e9 as int for
// any non-denormal magnitude) — no false match in practice.
__global__ __launch_bounds__(256) void k_scat_write(const int* __restrict__ coords,
                                                    const int* __restrict__ batch,
                                                    const float* __restrict__ outf,
                                                    int* __restrict__ dsti,
                                                    float* __restrict__ dstf, int n_total) {
    int n = blockIdx.x * blockDim.x + threadIdx.x;
    if (n >= n_total) return;
    int cell = cell_of(coords, batch, n);
    if (dsti[cell] == n + 1) dstf[cell] = outf[n];
}

extern "C" void kernel_launch(void* const* d_in, const int* in_sizes, int n_in,
                              void* d_out, int out_size, void* d_ws, size_t ws_size,
                              hipStream_t stream) {
    const float* feats    = (const float*)d_in[0];
    const float* w1       = (const float*)d_in[1];
    const float* w2       = (const float*)d_in[2];
    const float* w_out    = (const float*)d_in[3];
    const int*   nbr_idx  = (const int*)d_in[4];
    const int*   nbr_mask = (const int*)d_in[5];
    const int*   coords   = (const int*)d_in[6];
    const int*   batch    = (const int*)d_in[7];

    int n_total = in_sizes[0];  // feats is [N,1]
    float* h1   = (float*)d_ws;                       // N*8 floats = 4.8 MB
    float* outf = h1 + (size_t)n_total * CH;          // N floats   = 0.6 MB
    float* out  = (float*)d_out;

    int n4 = out_size / 4;
    k_zero<<<(n4 + 255) / 256, 256, 0, stream>>>((float4*)out, n4);

    int nb = (n_total + 255) / 256;
    k_h1<<<nb, 256, 0, stream>>>(feats, w1, nbr_idx, nbr_mask, h1, n_total);
    k_h2<<<nb, 256, 0, stream>>>(h1, w2, w_out, nbr_idx, nbr_mask, outf, n_total);
    k_scat_max<<<nb, 256, 0, stream>>>(coords, batch, (int*)out, n_total);
    k_scat_write<<<nb, 256, 0, stream>>>(coords, batch, outf, (int*)out, out, n_total);
}

// Round 2
// 431.473 us; speedup vs baseline: 2.0028x; 2.0028x over previous
//
#include <hip/hip_runtime.h>
#include <hip/hip_fp16.h>

// SparseEncoder4D: gather-GEMM-scatter sparse conv (1->8->8->1) + dense scatter.
// R2: (a) h1 gather table stored fp16 (2.4 MB < 4 MiB/XCD L2 -> L2-resident
// gathers; fp32 4.8 MB table was 1.87 GB of L2-miss traffic), (b) k-dim split
// across grid.y=3 (9.2 -> 27.5 waves/CU; gather-latency-bound needs waves).

#define KK 81
#define CH 8
#define KC 27   // k per y-chunk
#define NY 3    // y-chunks (KC*NY == KK)
#define BB 2
#define TT 4
#define ZZ 32
#define YY 256
#define XX 256

typedef __attribute__((ext_vector_type(8))) _Float16 half8;  // 16 B

__global__ __launch_bounds__(256) void k_zero(float4* __restrict__ out, int n4) {
    int i = blockIdx.x * blockDim.x + threadIdx.x;
    if (i < n4) out[i] = make_float4(0.f, 0.f, 0.f, 0.f);
}

// Layer 1 partial: part[y][n][c] = sum_{k in chunk y} mask*feats[nbr]*w1[k,0,c]
__global__ __launch_bounds__(256) void k_h1p(const float* __restrict__ feats,
                                             const float* __restrict__ w1,
                                             const int* __restrict__ nbr_idx,
                                             const int* __restrict__ nbr_mask,
                                             float* __restrict__ part, int n_total) {
    int n = blockIdx.x * blockDim.x + threadIdx.x;
    int y = blockIdx.y;
    if (n >= n_total) return;
    const int* ip = nbr_idx + (long)n * KK + y * KC;
    const int* mp = nbr_mask + (long)n * KK + y * KC;
    const float* wp = w1 + y * KC * CH;   // wave-uniform -> s_load
    float acc[CH];
#pragma unroll
    for (int c = 0; c < CH; c++) acc[c] = 0.f;
#pragma unroll 9
    for (int k = 0; k < KC; k++) {
        float fm = (float)mp[k];
        float f = feats[ip[k]] * fm;      // 4B gather, 600 KB table (L2-resident)
#pragma unroll
        for (int c = 0; c < CH; c++) acc[c] += f * wp[k * CH + c];
    }
    float4* o = (float4*)(part + ((long)y * n_total + n) * CH);
    o[0] = make_float4(acc[0], acc[1], acc[2], acc[3]);
    o[1] = make_float4(acc[4], acc[5], acc[6], acc[7]);
}

// Sum 3 partials, relu, pack to fp16 gather table.
__global__ __launch_bounds__(256) void k_pack1(const float* __restrict__ part,
                                               half8* __restrict__ h1, int n_total) {
    int n = blockIdx.x * blockDim.x + threadIdx.x;
    if (n >= n_total) return;
    const float4* p0 = (const float4*)(part + (long)n * CH);
    const float4* p1 = (const float4*)(part + ((long)n_total + n) * CH);
    const float4* p2 = (const float4*)(part + ((long)2 * n_total + n) * CH);
    float4 a0 = p0[0], a1 = p0[1], b0 = p1[0], b1 = p1[1], c0 = p2[0], c1 = p2[1];
    half8 r;
    r[0] = (_Float16)fmaxf(a0.x + b0.x + c0.x, 0.f);
    r[1] = (_Float16)fmaxf(a0.y + b0.y + c0.y, 0.f);
    r[2] = (_Float16)fmaxf(a0.z + b0.z + c0.z, 0.f);
    r[3] = (_Float16)fmaxf(a0.w + b0.w + c0.w, 0.f);
    r[4] = (_Float16)fmaxf(a1.x + b1.x + c1.x, 0.f);
    r[5] = (_Float16)fmaxf(a1.y + b1.y + c1.y, 0.f);
    r[6] = (_Float16)fmaxf(a1.z + b1.z + c1.z, 0.f);
    r[7] = (_Float16)fmaxf(a1.w + b1.w + c1.w, 0.f);
    h1[n] = r;
}

// Layer 2 partial: part[y][n][d] = sum_{k in chunk y, c} mask*h1[nbr][c]*w2[k,c,d]
__global__ __launch_bounds__(256) void k_h2p(const half8* __restrict__ h1,
                                             const float* __restrict__ w2,
                                             const int* __restrict__ nbr_idx,
                                             const int* __restrict__ nbr_mask,
                                             float* __restrict__ part, int n_total) {
    int n = blockIdx.x * blockDim.x + threadIdx.x;
    int y = blockIdx.y;
    if (n >= n_total) return;
    const int* ip = nbr_idx + (long)n * KK + y * KC;
    const int* mp = nbr_mask + (long)n * KK + y * KC;
    float acc[CH];
#pragma unroll
    for (int c = 0; c < CH; c++) acc[c] = 0.f;
#pragma unroll 3
    for (int k = 0; k < KC; k++) {
        float fm = (float)mp[k];
        half8 hv = h1[ip[k]];             // 16B gather, 2.4 MB table (L2-resident)
        float g[CH];
#pragma unroll
        for (int c = 0; c < CH; c++) g[c] = (float)hv[c] * fm;
        const float* wk = w2 + ((long)(y * KC + k)) * CH * CH;  // wave-uniform
#pragma unroll
        for (int d = 0; d < CH; d++) {
            acc[d] += g[0] * wk[0 * CH + d] + g[1] * wk[1 * CH + d] +
                      g[2] * wk[2 * CH + d] + g[3] * wk[3 * CH + d] +
                      g[4] * wk[4 * CH + d] + g[5] * wk[5 * CH + d] +
                      g[6] * wk[6 * CH + d] + g[7] * wk[7 * CH + d];
        }
    }
    float4* o = (float4*)(part + ((long)y * n_total + n) * CH);
    o[0] = make_float4(acc[0], acc[1], acc[2], acc[3]);
    o[1] = make_float4(acc[4], acc[5], acc[6], acc[7]);
}

// Sum 3 partials, relu, dot with w_out -> outf[n]
__global__ __launch_bounds__(256) void k_fin(const float* __restrict__ part,
                                             const float* __restrict__ w_out,
                                             float* __restrict__ outf, int n_total) {
    int n = blockIdx.x * blockDim.x + threadIdx.x;
    if (n >= n_total) return;
    const float4* p0 = (const float4*)(part + (long)n * CH);
    const float4* p1 = (const float4*)(part + ((long)n_total + n) * CH);
    const float4* p2 = (const float4*)(part + ((long)2 * n_total + n) * CH);
    float4 a0 = p0[0], a1 = p0[1], b0 = p1[0], b1 = p1[1], c0 = p2[0], c1 = p2[1];
    float s[CH];
    s[0] = a0.x + b0.x + c0.x; s[1] = a0.y + b0.y + c0.y;
    s[2] = a0.z + b0.z + c0.z; s[3] = a0.w + b0.w + c0.w;
    s[4] = a1.x + b1.x + c1.x; s[5] = a1.y + b1.y + c1.y;
    s[6] = a1.z + b1.z + c1.z; s[7] = a1.w + b1.w + c1.w;
    float o = 0.f;
#pragma unroll
    for (int c = 0; c < CH; c++) o += fmaxf(s[c], 0.f) * w_out[c];
    outf[n] = o;
}

__device__ __forceinline__ int cell_of(const int* coords, const int* batch, int n) {
    int4 c = *(const int4*)(coords + 4 * n);  // (x, y, z, t)
    int b = batch[n];
    return (((b * TT + c.w) * ZZ + c.z) * YY + c.y) * XX + c.x;
}

// Deterministic last-write-wins scatter: winner = max n.
__global__ __launch_bounds__(256) void k_scat_max(const int* __restrict__ coords,
                                                  const int* __restrict__ batch,
                                                  int* __restrict__ dsti, int n_total) {
    int n = blockIdx.x * blockDim.x + threadIdx.x;
    if (n >= n_total) return;
    atomicMax(dsti + cell_of(coords, batch, n), n + 1);
}

__global__ __launch_bounds__(256) void k_scat_write(const int* __restrict__ coords,
                                                    const int* __restrict__ batch,
                                                    const float* __restrict__ outf,
                                                    int* __restrict__ dsti,
                                                    float* __restrict__ dstf, int n_total) {
    int n = blockIdx.x * blockDim.x + threadIdx.x;
    if (n >= n_total) return;
    int cell = cell_of(coords, batch, n);
    if (dsti[cell] == n + 1) dstf[cell] = outf[n];
}

extern "C" void kernel_launch(void* const* d_in, const int* in_sizes, int n_in,
                              void* d_out, int out_size, void* d_ws, size_t ws_size,
                              hipStream_t stream) {
    const float* feats    = (const float*)d_in[0];
    const float* w1       = (const float*)d_in[1];
    const float* w2       = (const float*)d_in[2];
    const float* w_out    = (const float*)d_in[3];
    const int*   nbr_idx  = (const int*)d_in[4];
    const int*   nbr_mask = (const int*)d_in[5];
    const int*   coords   = (const int*)d_in[6];
    const int*   batch    = (const int*)d_in[7];

    int n_total = in_sizes[0];
    // ws layout: h1 fp16 table (16B*N = 2.4 MB) | part fp32 (3*N*8 = 14.4 MB) | outf (0.6 MB)
    half8* h1   = (half8*)d_ws;
    float* part = (float*)((char*)d_ws + (size_t)n_total * sizeof(half8));
    float* outf = part + (size_t)NY * n_total * CH;
    float* out  = (float*)d_out;

    int n4 = out_size / 4;
    k_zero<<<(n4 + 255) / 256, 256, 0, stream>>>((float4*)out, n4);

    int nb = (n_total + 255) / 256;
    dim3 gsplit(nb, NY);
    k_h1p<<<gsplit, 256, 0, stream>>>(feats, w1, nbr_idx, nbr_mask, part, n_total);
    k_pack1<<<nb, 256, 0, stream>>>(part, h1, n_total);
    k_h2p<<<gsplit, 256, 0, stream>>>(h1, w2, nbr_idx, nbr_mask, part, n_total);
    k_fin<<<nb, 256, 0, stream>>>(part, w_out, outf, n_total);
    k_scat_max<<<nb, 256, 0, stream>>>(coords, batch, (int*)out, n_total);
    k_scat_write<<<nb, 256, 0, stream>>>(coords, batch, outf, (int*)out, out, n_total);
}